// Round 3
// baseline (99.898 us; speedup 1.0000x reference)
//
#include <hip/hip_runtime.h>

// HyperLinear, fully fused:
//   setup_kernel: build Bb[832][256] bf16 (rows: 512 permuted fcwp_w, 64 c-rows,
//                 256 target_w) and B2[256][96] bf16 (fcwe_w | fcbp_w | fcwe_b |
//                 bias_const | zeros).
//   fused_kernel: per block = 16 samples.
//     GEMM1: Y[16][832] = x_bf16 @ Bb^T, consumed tile-by-tile:
//       tiles 0..7  -> t[s][m] = sum_p h[s][p]*Y[s][m*8+p]
//       tile  8     -> t[s][m] += Y[s][512+m]          (c contribution)
//       tiles 9..12 -> kept in regs as y-base fragments (x @ target_w^T)
//     GEMM2: out = ybase + [t | h | sx | 1] @ B2^T   (K=96, 12 MFMAs/wave)

#define B_TOT 2048
#define NP    8
#define CIN   256
#define COUT  256
#define MID   64
#define LDA   264    // As row stride (bf16): 528B, %16==0, bank-step 4
#define LDB   264    // Bs row stride
#define LDY   66     // Ytile row stride (fp32)
#define LDT   72     // t row stride (fp32)
#define LDA2  104    // A2 row stride (bf16): 208B, %16==0

typedef short  short8  __attribute__((ext_vector_type(8)));
typedef float  floatx4 __attribute__((ext_vector_type(4)));

__device__ __forceinline__ unsigned short f2bf(float f) {
    union { float f; unsigned u; } v; v.f = f;
    unsigned r = v.u + 0x7FFFu + ((v.u >> 16) & 1u);
    return (unsigned short)(r >> 16);
}
__device__ __forceinline__ float bf2f(unsigned short u) {
    union { unsigned u; float f; } v; v.u = ((unsigned)u) << 16;
    return v.f;
}

// ---------------- setup: build Bb and B2 (bf16) ----------------
__global__ __launch_bounds__(256) void setup_kernel(
    const float* __restrict__ index,
    const float* __restrict__ target_w, const float* __restrict__ target_b,
    const float* __restrict__ fcwp_w, const float* __restrict__ fcwp_b,
    const float* __restrict__ fcwi_w, const float* __restrict__ fcwi_b,
    const float* __restrict__ fcwe_w, const float* __restrict__ fcwe_b,
    const float* __restrict__ fcbp_w, const float* __restrict__ fcbp_b,
    const float* __restrict__ fcbi_w, const float* __restrict__ fcbi_b,
    unsigned short* __restrict__ Bb, unsigned short* __restrict__ B2)
{
    int gid = blockIdx.x * 256 + threadIdx.x;
    if (gid < 131072) {                        // permuted fcwp_w rows [0,512)
        int e = gid;                           // e = i*512 + m*8 + p
        int n = e & 511, i = e >> 9;
        Bb[n * CIN + i] = f2bf(fcwp_w[e]);
    } else if (gid < 147456) {                 // c rows [512,576)
        int e = gid - 131072;                  // e = i*64 + m
        int i = e >> 6, m = e & 63;
        float v = fcwp_b[e] + fcwi_b[e]
                + index[0] * fcwi_w[e * 4]     + index[1] * fcwi_w[e * 4 + 1]
                + index[2] * fcwi_w[e * 4 + 2] + index[3] * fcwi_w[e * 4 + 3];
        Bb[(512 + m) * CIN + i] = f2bf(v);
    } else if (gid < 212992) {                 // target_w rows [576,832)
        int e = gid - 147456;
        Bb[576 * CIN + e] = f2bf(target_w[e]);
    } else if (gid < 229376) {                 // B2 cols 0..63 = fcwe_w
        int e = gid - 212992;
        int o = e >> 6, m = e & 63;
        B2[o * 96 + m] = f2bf(fcwe_w[e]);
    } else if (gid < 231424) {                 // B2 cols 64..71 = fcbp_w
        int e = gid - 229376;
        int o = e >> 3, p = e & 7;
        B2[o * 96 + 64 + p] = f2bf(fcbp_w[e]);
    } else if (gid < 231680) {                 // B2 cols 72..95
        int o = gid - 231424;
        B2[o * 96 + 72] = f2bf(fcwe_b[o]);
        float bc = target_b[o] + fcbp_b[o] + fcbi_b[o]
                 + index[0] * fcbi_w[o * 4]     + index[1] * fcbi_w[o * 4 + 1]
                 + index[2] * fcbi_w[o * 4 + 2] + index[3] * fcbi_w[o * 4 + 3];
        B2[o * 96 + 73] = f2bf(bc);
        #pragma unroll
        for (int z = 74; z < 96; ++z) B2[o * 96 + z] = 0;
    }
}

// ---------------- fused GEMM + epilogue ----------------
__global__ __launch_bounds__(256) void fused_kernel(
    const float* __restrict__ x,              // [2048][256]
    const float* __restrict__ h,              // [2048][8]
    const unsigned short* __restrict__ Bb,    // [832][256] bf16
    const unsigned short* __restrict__ B2,    // [256][96]  bf16
    float* __restrict__ out)                  // [2048][256]
{
    __shared__ unsigned short As[16 * LDA];   // 8448 B
    __shared__ unsigned short Bs[64 * LDB];   // 33792 B
    __shared__ float Yt[16 * LDY];            // 4224 B
    __shared__ float tl[16][LDT];             // 4608 B
    __shared__ float hl[16][NP];
    __shared__ float ps[16][16];
    __shared__ float sxl[16];
    __shared__ unsigned short A2[16 * LDA2];  // 3328 B

    const int tid  = threadIdx.x;
    const int lane = tid & 63, w = tid >> 6;
    const int col  = lane & 15, quad = lane >> 4;
    const int b0   = blockIdx.x * 16;

    // stage As (x -> bf16): 16 rows x 256 = 1024 float4
    #pragma unroll
    for (int it = 0; it < 4; ++it) {
        int idx = it * 256 + tid;
        int r = idx >> 6, c = (idx & 63) * 4;
        float4 v = *(const float4*)(x + (size_t)(b0 + r) * CIN + c);
        ushort4 o4;
        o4.x = f2bf(v.x); o4.y = f2bf(v.y); o4.z = f2bf(v.z); o4.w = f2bf(v.w);
        *(ushort4*)&As[r * LDA + c] = o4;
    }
    if (tid < 16 * NP) hl[tid >> 3][tid & 7] = h[(size_t)b0 * NP + tid];
    __syncthreads();

    // sx[s] = sum_i x_bf16[s][i]
    {
        int s = tid >> 4, seg = tid & 15;
        float p = 0.f;
        #pragma unroll
        for (int j = 0; j < 16; ++j) p += bf2f(As[s * LDA + seg * 16 + j]);
        ps[s][seg] = p;
    }
    __syncthreads();
    if (tid < 16) {
        float p = 0.f;
        #pragma unroll
        for (int j = 0; j < 16; ++j) p += ps[tid][j];
        sxl[tid] = p;
    }

    floatx4 ybase[4];

    for (int nt = 0; nt < 13; ++nt) {
        __syncthreads();                      // Bs / Yt reuse barrier
        #pragma unroll
        for (int it = 0; it < 8; ++it) {      // stage Bs: 64 rows x 512B
            int idx = it * 256 + tid;
            int r = idx >> 5, ch = (idx & 31) * 8;
            uint4 v = *(const uint4*)(Bb + (size_t)(nt * 64 + r) * CIN + ch);
            *(uint4*)&Bs[r * LDB + ch] = v;
        }
        __syncthreads();

        floatx4 acc = floatx4{0.f, 0.f, 0.f, 0.f};
        #pragma unroll
        for (int ks = 0; ks < 8; ++ks) {
            int kc = ks * 32 + quad * 8;
            short8 af = *(const short8*)&As[col * LDA + kc];
            short8 bf = *(const short8*)&Bs[(w * 16 + col) * LDB + kc];
            acc = __builtin_amdgcn_mfma_f32_16x16x32_bf16(af, bf, acc, 0, 0, 0);
        }

        if (nt < 8) {
            #pragma unroll
            for (int r = 0; r < 4; ++r)
                Yt[(quad * 4 + r) * LDY + w * 16 + col] = acc[r];
            __syncthreads();
            if (tid < 128) {
                int s = tid >> 3, ml = tid & 7;
                float tv = 0.f;
                #pragma unroll
                for (int p = 0; p < NP; ++p)
                    tv += hl[s][p] * Yt[s * LDY + ml * 8 + p];
                tl[s][nt * 8 + ml] = tv;
            }
        } else if (nt == 8) {
            #pragma unroll
            for (int r = 0; r < 4; ++r)
                Yt[(quad * 4 + r) * LDY + w * 16 + col] = acc[r];
            __syncthreads();
            #pragma unroll
            for (int it = 0; it < 4; ++it) {
                int idx = it * 256 + tid;
                int s = idx >> 6, m = idx & 63;
                tl[s][m] += Yt[s * LDY + m];
            }
        } else {
            ybase[nt - 9] = acc;
        }
    }
    __syncthreads();

    // build A2 = [t | h | sx | 1 | 0...]  (16 x 96, stride LDA2)
    #pragma unroll
    for (int it = 0; it < 4; ++it) {
        int idx = it * 256 + tid;
        int s = idx >> 6, m = idx & 63;
        A2[s * LDA2 + m] = f2bf(tl[s][m]);
    }
    if (tid < 128) A2[(tid >> 3) * LDA2 + 64 + (tid & 7)] = f2bf(hl[tid >> 3][tid & 7]);
    if (tid < 16) {
        A2[tid * LDA2 + 72] = f2bf(sxl[tid]);
        A2[tid * LDA2 + 73] = 0x3F80;         // 1.0 bf16
    }
    for (int idx = tid; idx < 16 * 22; idx += 256) {
        int s = idx / 22, cc = 74 + idx % 22;
        A2[s * LDA2 + cc] = 0;
    }
    __syncthreads();

    // GEMM2: out = ybase + A2 @ B2^T ; wave w handles o-slices j*64 + w*16
    floatx4 y2[4];
    #pragma unroll
    for (int j = 0; j < 4; ++j) y2[j] = ybase[j];
    #pragma unroll
    for (int ks = 0; ks < 3; ++ks) {
        int kc = ks * 32 + quad * 8;
        short8 af = *(const short8*)&A2[col * LDA2 + kc];
        #pragma unroll
        for (int j = 0; j < 4; ++j) {
            short8 bf = *(const short8*)(B2 + (size_t)(j * 64 + w * 16 + col) * 96 + kc);
            y2[j] = __builtin_amdgcn_mfma_f32_16x16x32_bf16(af, bf, y2[j], 0, 0, 0);
        }
    }
    #pragma unroll
    for (int j = 0; j < 4; ++j)
        #pragma unroll
        for (int r = 0; r < 4; ++r)
            out[(size_t)(b0 + quad * 4 + r) * COUT + j * 64 + w * 16 + col] = y2[j][r];
}

extern "C" void kernel_launch(void* const* d_in, const int* in_sizes, int n_in,
                              void* d_out, int out_size, void* d_ws, size_t ws_size,
                              hipStream_t stream) {
    const float* x        = (const float*)d_in[0];
    const float* h        = (const float*)d_in[1];
    const float* index    = (const float*)d_in[2];
    const float* target_w = (const float*)d_in[3];
    const float* target_b = (const float*)d_in[4];
    const float* fcwp_w   = (const float*)d_in[5];
    const float* fcwp_b   = (const float*)d_in[6];
    const float* fcwi_w   = (const float*)d_in[7];
    const float* fcwi_b   = (const float*)d_in[8];
    const float* fcwe_w   = (const float*)d_in[9];
    const float* fcwe_b   = (const float*)d_in[10];
    const float* fcbp_w   = (const float*)d_in[11];
    const float* fcbp_b   = (const float*)d_in[12];
    const float* fcbi_w   = (const float*)d_in[13];
    const float* fcbi_b   = (const float*)d_in[14];
    float* out = (float*)d_out;

    char* ws = (char*)d_ws;
    unsigned short* Bb = (unsigned short*)ws;             // 832*256*2 = 425984 B
    unsigned short* B2 = (unsigned short*)(ws + 425984);  // 256*96*2  =  49152 B

    setup_kernel<<<905, 256, 0, stream>>>(
        index, target_w, target_b, fcwp_w, fcwp_b, fcwi_w, fcwi_b,
        fcwe_w, fcwe_b, fcbp_w, fcbp_b, fcbi_w, fcbi_b, Bb, B2);

    fused_kernel<<<B_TOT / 16, 256, 0, stream>>>(x, h, Bb, B2, out);
}